// Round 6
// baseline (152.919 us; speedup 1.0000x reference)
//
#include <hip/hip_runtime.h>
#include <math.h>

#define BATCH   16384
#define IMGPIX  784           // 28*28
#define NTOT    (BATCH * IMGPIX)
#define NSLOT   64            // atomic spread slots per stage
#define SLOTSTR 8             // doubles per slot (64B stride); [0]=sum [1]=sumsq
#define STAGE_DBL (NSLOT * SLOTSTR)

// ---------------- stats helpers ----------------
__device__ __forceinline__ void wave_stats_atomic(float lsum, float lsq, double* slot) {
    #pragma unroll
    for (int off = 32; off >= 1; off >>= 1) {
        lsum += __shfl_down(lsum, off, 64);
        lsq  += __shfl_down(lsq,  off, 64);
    }
    if ((threadIdx.x & 63) == 0) {
        atomicAdd(&slot[0], (double)lsum);
        atomicAdd(&slot[1], (double)lsq);
    }
}

// Per-wave: reduce the 64 stat slots (2 doubles per lane), broadcast; returns
// (a,b) with bn(x) = a*x + b. No barrier needed.
__device__ __forceinline__ float2 stats_ab(const double* __restrict__ stats_in,
                                           float gamma, float beta) {
    int lane = threadIdx.x & 63;
    double s = stats_in[lane * SLOTSTR];
    double q = stats_in[lane * SLOTSTR + 1];
    #pragma unroll
    for (int off = 32; off >= 1; off >>= 1) {
        s += __shfl_down(s, off, 64);
        q += __shfl_down(q, off, 64);
    }
    s = __shfl(s, 0, 64);
    q = __shfl(q, 0, 64);
    const double INV_N = 1.0 / (double)NTOT;
    double mean = s * INV_N;
    double var  = q * INV_N - mean * mean;
    float rstd = 1.0f / sqrtf((float)var + 1e-5f);
    float a  = gamma * rstd;
    float bb = beta - (float)mean * a;
    return make_float2(a, bb);
}

// ---------------- strip conv core ----------------
// Grid: 2048 blocks = 512 image-groups x 4 strips. Strip s owns output rows
// r0..r0+6 (r0 = 7s), consumes input rows r0-1..r0+7 (zero outside image).
// Lane layout: lane = i*8 + c4 (i = image-in-wave 0..7, c4 = 0..6 column
// quad, c4==7 idle). Horizontal halo via shfl.

__device__ __forceinline__ float4 hrow(float wl, float wc, float wr,
                                       float L, float4 v, float R) {
    float4 h;
    h.x = fmaf(wl, L,   fmaf(wc, v.x, wr * v.y));
    h.y = fmaf(wl, v.x, fmaf(wc, v.y, wr * v.z));
    h.z = fmaf(wl, v.y, fmaf(wc, v.z, wr * v.w));
    h.w = fmaf(wl, v.z, fmaf(wc, v.w, wr * R));
    return h;
}

__device__ __forceinline__ void emit_row(float* dst, int r, float4 o, float mf,
                                         float& lsum, float& lsq, bool act) {
    if (act) *(float4*)(dst + r * 28) = o;
    float s4 = (o.x + o.y) + (o.z + o.w);
    float q4 = fmaf(o.x, o.x, fmaf(o.y, o.y, fmaf(o.z, o.z, o.w * o.w)));
    lsum = fmaf(mf, s4, lsum);
    lsq  = fmaf(mf, q4, lsq);
}

#define LANE_SETUP()                                                          \
    const int t = threadIdx.x;                                                \
    const int lane = t & 63;                                                  \
    const int widx = t >> 6;                                                  \
    const int c4   = lane & 7;                                                \
    const bool act = (c4 < 7);                                                \
    const float mf = act ? 1.f : 0.f;                                         \
    const int c4c  = c4 < 7 ? c4 : 6;  /* clamp idle lane addresses */        \
    const int g    = blockIdx.x & 511;   /* image group: same XCD for all 4 strips */ \
    const int s    = blockIdx.x >> 9;    /* strip 0..3 */                     \
    const int r0   = s * 7;                                                   \
    const int img  = g * 32 + widx * 8 + (lane >> 3);                         \
    const size_t ibase = (size_t)img * IMGPIX + c4c * 4;

// One pipeline step for input row k (global row r0-1+k); emits row r0+k-2 for k>=2.
#define CONV_STEP(k, v)                                                       \
    {                                                                         \
        float L = __shfl_up((v).w, 1, 64);  if (c4 == 0) L = 0.f;             \
        float R = __shfl_down((v).x, 1, 64); if (c4 == 6) R = 0.f;            \
        float4 h2 = hrow(w9[6], w9[7], w9[8], L, (v), R);                     \
        float4 h1 = hrow(w9[3], w9[4], w9[5], L, (v), R);                     \
        float4 h0 = hrow(w9[0], w9[1], w9[2], L, (v), R);                     \
        accA.x += h2.x; accA.y += h2.y; accA.z += h2.z; accA.w += h2.w;       \
        if ((k) >= 2) emit_row(dst, r0 + (k) - 2, accA, mf, lsum, lsq, act);  \
        accA.x = accB.x + h1.x; accA.y = accB.y + h1.y;                       \
        accA.z = accB.z + h1.z; accA.w = accB.w + h1.w;                       \
        accB = h0;                                                            \
    }

#define ZERO4 make_float4(0.f, 0.f, 0.f, 0.f)

// Pass 1: y1 = conv(x, w); stats(y1)
__global__ __launch_bounds__(256, 5) void k_conv_plain(const float* __restrict__ in,
        const float* __restrict__ w, float* __restrict__ out, double* __restrict__ stats_out)
{
    LANE_SETUP();
    float w9[9];
    #pragma unroll
    for (int i = 0; i < 9; i++) w9[i] = w[i];
    const float* src = in + ibase;
    float* dst = out + (size_t)img * IMGPIX + c4 * 4;

    float4 vb[9];
    vb[0] = (r0 > 0)  ? *(const float4*)(src + (r0 - 1) * 28) : ZERO4;
    #pragma unroll
    for (int k = 1; k < 8; k++) vb[k] = *(const float4*)(src + (r0 - 1 + k) * 28);
    vb[8] = (r0 < 21) ? *(const float4*)(src + (r0 + 7) * 28) : ZERO4;

    float4 accA = ZERO4, accB = ZERO4;
    float lsum = 0.f, lsq = 0.f;
    #pragma unroll
    for (int k = 0; k < 9; k++) CONV_STEP(k, vb[k]);
    wave_stats_atomic(lsum, lsq, &stats_out[((blockIdx.x * 4 + widx) & (NSLOT - 1)) * SLOTSTR]);
}

// Pass 2/4: h = relu(bn(in)); y = conv(h, w); stats(y)
__global__ __launch_bounds__(256, 5) void k_conv_affine(const float* __restrict__ in,
        const double* __restrict__ stats_in,
        const float* __restrict__ gamma, const float* __restrict__ beta,
        const float* __restrict__ w, float* __restrict__ out, double* __restrict__ stats_out)
{
    LANE_SETUP();
    float2 ab = stats_ab(stats_in, gamma[0], beta[0]);
    float w9[9];
    #pragma unroll
    for (int i = 0; i < 9; i++) w9[i] = w[i];
    const float* src = in + ibase;
    float* dst = out + (size_t)img * IMGPIX + c4 * 4;

    float4 vb[9];
    vb[0] = (r0 > 0)  ? *(const float4*)(src + (r0 - 1) * 28) : ZERO4;
    #pragma unroll
    for (int k = 1; k < 8; k++) vb[k] = *(const float4*)(src + (r0 - 1 + k) * 28);
    vb[8] = (r0 < 21) ? *(const float4*)(src + (r0 + 7) * 28) : ZERO4;

    float4 accA = ZERO4, accB = ZERO4;
    float lsum = 0.f, lsq = 0.f;
    #pragma unroll
    for (int k = 0; k < 9; k++) {
        float4 r4 = vb[k];
        float4 v;
        v.x = fmaxf(fmaf(ab.x, r4.x, ab.y), 0.f);
        v.y = fmaxf(fmaf(ab.x, r4.y, ab.y), 0.f);
        v.z = fmaxf(fmaf(ab.x, r4.z, ab.y), 0.f);
        v.w = fmaxf(fmaf(ab.x, r4.w, ab.y), 0.f);
        CONV_STEP(k, v);
    }
    wave_stats_atomic(lsum, lsq, &stats_out[((blockIdx.x * 4 + widx) & (NSLOT - 1)) * SLOTSTR]);
}

// Pass 3: o1 = relu(bn(y2) + x) [stored, owned rows]; y3 = conv(o1, w); stats(y3)
__global__ __launch_bounds__(256, 4) void k_conv_resid(const float* __restrict__ y2,
        const float* __restrict__ x, const double* __restrict__ stats_in,
        const float* __restrict__ gamma, const float* __restrict__ beta,
        const float* __restrict__ w, float* __restrict__ y3_out,
        float* __restrict__ o1_out, double* __restrict__ stats_out)
{
    LANE_SETUP();
    float2 ab = stats_ab(stats_in, gamma[0], beta[0]);
    float w9[9];
    #pragma unroll
    for (int i = 0; i < 9; i++) w9[i] = w[i];
    const float* srcy = y2 + ibase;
    const float* srcx = x + ibase;
    float* dst  = y3_out + (size_t)img * IMGPIX + c4 * 4;
    float* dsto = o1_out + (size_t)img * IMGPIX + c4 * 4;

    float4 yb[9], xb[9];
    yb[0] = (r0 > 0)  ? *(const float4*)(srcy + (r0 - 1) * 28) : ZERO4;
    xb[0] = (r0 > 0)  ? *(const float4*)(srcx + (r0 - 1) * 28) : ZERO4;
    #pragma unroll
    for (int k = 1; k < 8; k++) {
        yb[k] = *(const float4*)(srcy + (r0 - 1 + k) * 28);
        xb[k] = *(const float4*)(srcx + (r0 - 1 + k) * 28);
    }
    yb[8] = (r0 < 21) ? *(const float4*)(srcy + (r0 + 7) * 28) : ZERO4;
    xb[8] = (r0 < 21) ? *(const float4*)(srcx + (r0 + 7) * 28) : ZERO4;

    float4 accA = ZERO4, accB = ZERO4;
    float lsum = 0.f, lsq = 0.f;
    #pragma unroll
    for (int k = 0; k < 9; k++) {
        float4 r4 = yb[k];
        float4 x4 = xb[k];
        float4 v;
        v.x = fmaxf(fmaf(ab.x, r4.x, ab.y) + x4.x, 0.f);
        v.y = fmaxf(fmaf(ab.x, r4.y, ab.y) + x4.y, 0.f);
        v.z = fmaxf(fmaf(ab.x, r4.z, ab.y) + x4.z, 0.f);
        v.w = fmaxf(fmaf(ab.x, r4.w, ab.y) + x4.w, 0.f);
        if (act && k >= 1 && k <= 7)           // owned rows only
            *(float4*)(dsto + (r0 - 1 + k) * 28) = v;
        CONV_STEP(k, v);
    }
    wave_stats_atomic(lsum, lsq, &stats_out[((blockIdx.x * 4 + widx) & (NSLOT - 1)) * SLOTSTR]);
}

// Pass 5: o2 = relu(bn(y4)+o1); logits = alpha*(o2@fcW^T)+qk; log_softmax
#define FC_LD 11
__global__ __launch_bounds__(256) void k_head(const float* __restrict__ y4,
        const float* __restrict__ o1, const double* __restrict__ stats_in,
        const float* __restrict__ gamma, const float* __restrict__ beta,
        const float* __restrict__ fc_w, const float* __restrict__ qk,
        const float* __restrict__ alpha_p, float* __restrict__ out)
{
    __shared__ float fcT[IMGPIX * FC_LD];
    const int t = threadIdx.x;
    float2 ab = stats_ab(stats_in, gamma[0], beta[0]);
    for (int i = t; i < 7840; i += 256) {
        int k = i / 784;
        int j = i - k * 784;
        fcT[j * FC_LD + k] = fc_w[i];
    }
    float alpha = alpha_p[0];
    float qkr[10];
    #pragma unroll
    for (int k = 0; k < 10; k++) qkr[k] = qk[k];
    __syncthreads();

    const int wid  = t >> 6;
    const int lane = t & 63;
    const int row  = blockIdx.x * 4 + wid;   // grid=4096 -> rows 0..16383
    const float* yr   = y4 + (size_t)row * IMGPIX;
    const float* orow = o1 + (size_t)row * IMGPIX;

    float acc[10];
    #pragma unroll
    for (int k = 0; k < 10; k++) acc[k] = 0.f;
    for (int j = lane; j < IMGPIX; j += 64) {
        float v = fmaxf(fmaf(ab.x, yr[j], ab.y) + orow[j], 0.f);
        const float* fr = &fcT[j * FC_LD];
        #pragma unroll
        for (int k = 0; k < 10; k++) acc[k] = fmaf(v, fr[k], acc[k]);
    }
    #pragma unroll
    for (int k = 0; k < 10; k++) {
        #pragma unroll
        for (int off = 1; off < 64; off <<= 1)
            acc[k] += __shfl_xor(acc[k], off, 64);
    }
    float logit[10];
    float m = -1e30f;
    #pragma unroll
    for (int k = 0; k < 10; k++) {
        logit[k] = fmaf(alpha, acc[k], qkr[k]);
        m = fmaxf(m, logit[k]);
    }
    float se = 0.f;
    #pragma unroll
    for (int k = 0; k < 10; k++) se += __expf(logit[k] - m);
    float lse = m + __logf(se);
    if (lane < 10) out[(size_t)row * 10 + lane] = logit[lane] - lse;
}

// Init: zero stats, compute qk[10] = (1-alpha)*c2*sum_{j%4==0} fcw[k,j] + fcb[k]
__global__ __launch_bounds__(256) void k_init(const float* __restrict__ theta,
        const float* __restrict__ fc_w, const float* __restrict__ fc_b,
        const float* __restrict__ alpha_p, float* __restrict__ qk, double* __restrict__ stats)
{
    const int t = threadIdx.x;
    for (int i = t; i < 4 * STAGE_DBL; i += 256) stats[i] = 0.0;
    if (t < 10) {
        float c = 1.f;
        #pragma unroll
        for (int i = 0; i < 24; i++) c *= cosf(theta[i] * 0.5f);
        float c2 = c * c;
        float s = 0.f;
        for (int j = 0; j < 784; j += 4) s += fc_w[t * 784 + j];
        qk[t] = (1.f - alpha_p[0]) * c2 * s + fc_b[t];
    }
}

extern "C" void kernel_launch(void* const* d_in, const int* in_sizes, int n_in,
                              void* d_out, int out_size, void* d_ws, size_t ws_size,
                              hipStream_t stream) {
    const float* x     = (const float*)d_in[0];
    const float* theta = (const float*)d_in[1];
    const float* r1_w1 = (const float*)d_in[2];
    const float* r1_g1 = (const float*)d_in[3];
    const float* r1_b1 = (const float*)d_in[4];
    const float* r1_w2 = (const float*)d_in[5];
    const float* r1_g2 = (const float*)d_in[6];
    const float* r1_b2 = (const float*)d_in[7];
    const float* r2_w1 = (const float*)d_in[8];
    const float* r2_g1 = (const float*)d_in[9];
    const float* r2_b1 = (const float*)d_in[10];
    const float* r2_w2 = (const float*)d_in[11];
    const float* r2_g2 = (const float*)d_in[12];
    const float* r2_b2 = (const float*)d_in[13];
    const float* fc_w  = (const float*)d_in[14];
    const float* fc_b  = (const float*)d_in[15];
    const float* alpha = (const float*)d_in[16];
    float* out = (float*)d_out;

    double* stats = (double*)d_ws;                       // 4 stages * 512 dbl = 16KB
    float*  qk    = (float*)((char*)d_ws + 16384);       // 10 floats
    float*  bufA  = (float*)((char*)d_ws + 32768);       // y1 then y3
    float*  bufB  = bufA + (size_t)NTOT;                 // y2 then y4
    float*  bufD  = bufB + (size_t)NTOT;                 // o1

    double* s_y1 = stats + 0 * STAGE_DBL;
    double* s_y2 = stats + 1 * STAGE_DBL;
    double* s_y3 = stats + 2 * STAGE_DBL;
    double* s_y4 = stats + 3 * STAGE_DBL;

    k_init<<<1, 256, 0, stream>>>(theta, fc_w, fc_b, alpha, qk, stats);
    k_conv_plain<<<2048, 256, 0, stream>>>(x, r1_w1, bufA, s_y1);
    k_conv_affine<<<2048, 256, 0, stream>>>(bufA, s_y1, r1_g1, r1_b1, r1_w2, bufB, s_y2);
    k_conv_resid<<<2048, 256, 0, stream>>>(bufB, x, s_y2, r1_g2, r1_b2, r2_w1, bufA, bufD, s_y3);
    k_conv_affine<<<2048, 256, 0, stream>>>(bufA, s_y3, r2_g1, r2_b1, r2_w2, bufB, s_y4);
    k_head<<<4096, 256, 0, stream>>>(bufB, bufD, s_y4, r2_g2, r2_b2, fc_w, qk, alpha, out);
}

// Round 7
// 137.922 us; speedup vs baseline: 1.1087x; 1.1087x over previous
//
#include <hip/hip_runtime.h>
#include <math.h>

#define BATCH   16384
#define IMGPIX  784           // 28*28
#define NTOT    (BATCH * IMGPIX)
#define NSLOT   64            // atomic spread slots per stage
#define SLOTSTR 8             // doubles per slot (64B stride); [0]=sum [1]=sumsq
#define STAGE_DBL (NSLOT * SLOTSTR)

// ---------------- stats helpers ----------------
__device__ __forceinline__ void wave_stats_atomic(double lsum, double lsq, double* slot) {
    #pragma unroll
    for (int off = 32; off >= 1; off >>= 1) {
        lsum += __shfl_down(lsum, off, 64);
        lsq  += __shfl_down(lsq,  off, 64);
    }
    if ((threadIdx.x & 63) == 0) {
        atomicAdd(&slot[0], lsum);
        atomicAdd(&slot[1], lsq);
    }
}

// Per-wave: reduce the 64 stat slots (2 doubles per lane), broadcast; returns
// (a,b) with bn(x) = a*x + b. No barrier needed.
__device__ __forceinline__ float2 stats_ab(const double* __restrict__ stats_in,
                                           float gamma, float beta) {
    int lane = threadIdx.x & 63;
    double s = stats_in[lane * SLOTSTR];
    double q = stats_in[lane * SLOTSTR + 1];
    #pragma unroll
    for (int off = 32; off >= 1; off >>= 1) {
        s += __shfl_down(s, off, 64);
        q += __shfl_down(q, off, 64);
    }
    s = __shfl(s, 0, 64);
    q = __shfl(q, 0, 64);
    const double INV_N = 1.0 / (double)NTOT;
    double mean = s * INV_N;
    double var  = q * INV_N - mean * mean;
    float rstd = 1.0f / sqrtf((float)var + 1e-5f);
    float a  = gamma * rstd;
    float bb = beta - (float)mean * a;
    return make_float2(a, bb);
}

// ---------------- strip conv core ----------------
// Grid: 2048 blocks = 512 image-groups x 4 strips. Strip s owns output rows
// r0..r0+6 (r0 = 7s), consumes conv-input rows r0-1..r0+7 (zero outside the
// image — zeroing happens on the ACTIVATED value, since reference pads h).
// Lane layout: lane = i*8 + c4 (i = image-in-wave 0..7, c4 = 0..6 column
// quad, c4==7 idle). Horizontal halo via shfl.

__device__ __forceinline__ float4 hrow(float wl, float wc, float wr,
                                       float L, float4 v, float R) {
    float4 h;
    h.x = fmaf(wl, L,   fmaf(wc, v.x, wr * v.y));
    h.y = fmaf(wl, v.x, fmaf(wc, v.y, wr * v.z));
    h.z = fmaf(wl, v.y, fmaf(wc, v.z, wr * v.w));
    h.w = fmaf(wl, v.z, fmaf(wc, v.w, wr * R));
    return h;
}

__device__ __forceinline__ void emit_row(float* dst, int r, float4 o, float mf,
                                         double& lsum, double& lsq, bool act) {
    if (act) *(float4*)(dst + r * 28) = o;
    float s4 = (o.x + o.y) + (o.z + o.w);
    float q4 = fmaf(o.x, o.x, fmaf(o.y, o.y, fmaf(o.z, o.z, o.w * o.w)));
    lsum += (double)(mf * s4);
    lsq  += (double)(mf * q4);
}

#define LANE_SETUP()                                                          \
    const int t = threadIdx.x;                                                \
    const int lane = t & 63;                                                  \
    const int widx = t >> 6;                                                  \
    const int c4   = lane & 7;                                                \
    const bool act = (c4 < 7);                                                \
    const float mf = act ? 1.f : 0.f;                                         \
    const int c4c  = c4 < 7 ? c4 : 6;  /* clamp idle lane addresses */        \
    const int g    = blockIdx.x & 511;   /* image group */                    \
    const int s    = blockIdx.x >> 9;    /* strip 0..3 */                     \
    const int r0   = s * 7;                                                   \
    const int rtop = (r0 > 0)  ? (r0 - 1) : 0;   /* clamped halo rows */      \
    const int rbot = (r0 < 21) ? (r0 + 7) : 27;                               \
    const int img  = g * 32 + widx * 8 + (lane >> 3);                         \
    const size_t ibase = (size_t)img * IMGPIX + c4c * 4;

// One pipeline step for conv-input row k (global row r0-1+k); emits row
// r0+k-2 for k>=2.
#define CONV_STEP(k, v)                                                       \
    {                                                                         \
        float L = __shfl_up((v).w, 1, 64);  if (c4 == 0) L = 0.f;             \
        float R = __shfl_down((v).x, 1, 64); if (c4 == 6) R = 0.f;            \
        float4 h2 = hrow(w9[6], w9[7], w9[8], L, (v), R);                     \
        float4 h1 = hrow(w9[3], w9[4], w9[5], L, (v), R);                     \
        float4 h0 = hrow(w9[0], w9[1], w9[2], L, (v), R);                     \
        accA.x += h2.x; accA.y += h2.y; accA.z += h2.z; accA.w += h2.w;       \
        if ((k) >= 2) emit_row(dst, r0 + (k) - 2, accA, mf, lsum, lsq, act);  \
        accA.x = accB.x + h1.x; accA.y = accB.y + h1.y;                       \
        accA.z = accB.z + h1.z; accA.w = accB.w + h1.w;                       \
        accB = h0;                                                            \
    }

// Zero the ACTIVATED conv-input value on out-of-image halo rows.
#define HALO_ZERO(k, v)                                                       \
    if ((k) == 0 && r0 == 0)  (v) = ZERO4;                                    \
    if ((k) == 8 && r0 == 21) (v) = ZERO4;

#define ZERO4 make_float4(0.f, 0.f, 0.f, 0.f)

// Pass 1: y1 = conv(x, w); stats(y1)
__global__ __launch_bounds__(256, 5) void k_conv_plain(const float* __restrict__ in,
        const float* __restrict__ w, float* __restrict__ out, double* __restrict__ stats_out)
{
    LANE_SETUP();
    float w9[9];
    #pragma unroll
    for (int i = 0; i < 9; i++) w9[i] = w[i];
    const float* src = in + ibase;
    float* dst = out + (size_t)img * IMGPIX + c4 * 4;

    float4 vb[9];
    vb[0] = *(const float4*)(src + rtop * 28);
    #pragma unroll
    for (int k = 1; k < 8; k++) vb[k] = *(const float4*)(src + (r0 - 1 + k) * 28);
    vb[8] = *(const float4*)(src + rbot * 28);
    __builtin_amdgcn_sched_barrier(0);     // keep all 9 loads issued upfront

    float4 accA = ZERO4, accB = ZERO4;
    double lsum = 0.0, lsq = 0.0;
    #pragma unroll
    for (int k = 0; k < 9; k++) {
        float4 v = vb[k];
        HALO_ZERO(k, v);                   // plain conv input = x, pad 0
        CONV_STEP(k, v);
    }
    wave_stats_atomic(lsum, lsq, &stats_out[((blockIdx.x * 4 + widx) & (NSLOT - 1)) * SLOTSTR]);
}

// Pass 2/4: h = relu(bn(in)); y = conv(h, w); stats(y)
__global__ __launch_bounds__(256, 5) void k_conv_affine(const float* __restrict__ in,
        const double* __restrict__ stats_in,
        const float* __restrict__ gamma, const float* __restrict__ beta,
        const float* __restrict__ w, float* __restrict__ out, double* __restrict__ stats_out)
{
    LANE_SETUP();
    float2 ab = stats_ab(stats_in, gamma[0], beta[0]);
    float w9[9];
    #pragma unroll
    for (int i = 0; i < 9; i++) w9[i] = w[i];
    const float* src = in + ibase;
    float* dst = out + (size_t)img * IMGPIX + c4 * 4;

    float4 vb[9];
    vb[0] = *(const float4*)(src + rtop * 28);
    #pragma unroll
    for (int k = 1; k < 8; k++) vb[k] = *(const float4*)(src + (r0 - 1 + k) * 28);
    vb[8] = *(const float4*)(src + rbot * 28);
    __builtin_amdgcn_sched_barrier(0);

    float4 accA = ZERO4, accB = ZERO4;
    double lsum = 0.0, lsq = 0.0;
    #pragma unroll
    for (int k = 0; k < 9; k++) {
        float4 r4 = vb[k];
        float4 v;
        v.x = fmaxf(fmaf(ab.x, r4.x, ab.y), 0.f);
        v.y = fmaxf(fmaf(ab.x, r4.y, ab.y), 0.f);
        v.z = fmaxf(fmaf(ab.x, r4.z, ab.y), 0.f);
        v.w = fmaxf(fmaf(ab.x, r4.w, ab.y), 0.f);
        HALO_ZERO(k, v);                   // pad AFTER activation (matches ref)
        CONV_STEP(k, v);
    }
    wave_stats_atomic(lsum, lsq, &stats_out[((blockIdx.x * 4 + widx) & (NSLOT - 1)) * SLOTSTR]);
}

// Pass 3: o1 = relu(bn(y2) + x) [stored, owned rows]; y3 = conv(o1, w); stats(y3)
__global__ __launch_bounds__(256, 4) void k_conv_resid(const float* __restrict__ y2,
        const float* __restrict__ x, const double* __restrict__ stats_in,
        const float* __restrict__ gamma, const float* __restrict__ beta,
        const float* __restrict__ w, float* __restrict__ y3_out,
        float* __restrict__ o1_out, double* __restrict__ stats_out)
{
    LANE_SETUP();
    float2 ab = stats_ab(stats_in, gamma[0], beta[0]);
    float w9[9];
    #pragma unroll
    for (int i = 0; i < 9; i++) w9[i] = w[i];
    const float* srcy = y2 + ibase;
    const float* srcx = x + ibase;
    float* dst  = y3_out + (size_t)img * IMGPIX + c4 * 4;
    float* dsto = o1_out + (size_t)img * IMGPIX + c4 * 4;

    float4 yb[9], xb[9];
    yb[0] = *(const float4*)(srcy + rtop * 28);
    xb[0] = *(const float4*)(srcx + rtop * 28);
    #pragma unroll
    for (int k = 1; k < 8; k++) {
        yb[k] = *(const float4*)(srcy + (r0 - 1 + k) * 28);
        xb[k] = *(const float4*)(srcx + (r0 - 1 + k) * 28);
    }
    yb[8] = *(const float4*)(srcy + rbot * 28);
    xb[8] = *(const float4*)(srcx + rbot * 28);
    __builtin_amdgcn_sched_barrier(0);     // keep all 18 loads issued upfront

    float4 accA = ZERO4, accB = ZERO4;
    double lsum = 0.0, lsq = 0.0;
    #pragma unroll
    for (int k = 0; k < 9; k++) {
        float4 r4 = yb[k];
        float4 x4 = xb[k];
        float4 v;
        v.x = fmaxf(fmaf(ab.x, r4.x, ab.y) + x4.x, 0.f);
        v.y = fmaxf(fmaf(ab.x, r4.y, ab.y) + x4.y, 0.f);
        v.z = fmaxf(fmaf(ab.x, r4.z, ab.y) + x4.z, 0.f);
        v.w = fmaxf(fmaf(ab.x, r4.w, ab.y) + x4.w, 0.f);
        HALO_ZERO(k, v);
        if (act && k >= 1 && k <= 7)           // owned rows only (always in-image)
            *(float4*)(dsto + (r0 - 1 + k) * 28) = v;
        CONV_STEP(k, v);
    }
    wave_stats_atomic(lsum, lsq, &stats_out[((blockIdx.x * 4 + widx) & (NSLOT - 1)) * SLOTSTR]);
}

// Pass 5: o2 = relu(bn(y4)+o1); logits = alpha*(o2@fcW^T)+qk; log_softmax
// 1024 blocks x 16 rows: fcT staged once per block, rows processed in pairs.
#define FC_LD 11
__global__ __launch_bounds__(256) void k_head(const float* __restrict__ y4,
        const float* __restrict__ o1, const double* __restrict__ stats_in,
        const float* __restrict__ gamma, const float* __restrict__ beta,
        const float* __restrict__ fc_w, const float* __restrict__ qk,
        const float* __restrict__ alpha_p, float* __restrict__ out)
{
    __shared__ float fcT[IMGPIX * FC_LD];
    const int t = threadIdx.x;
    float2 ab = stats_ab(stats_in, gamma[0], beta[0]);
    for (int i = t; i < 7840; i += 256) {
        int k = i / 784;
        int j = i - k * 784;
        fcT[j * FC_LD + k] = fc_w[i];
    }
    float alpha = alpha_p[0];
    float qkr[10];
    #pragma unroll
    for (int k = 0; k < 10; k++) qkr[k] = qk[k];
    __syncthreads();

    const int wid  = t >> 6;
    const int lane = t & 63;
    const int rbase = blockIdx.x * 16 + wid * 4;   // 4 rows per wave

    #pragma unroll
    for (int rp = 0; rp < 2; rp++) {
        const int r0 = rbase + rp * 2;
        const float* ya = y4 + (size_t)r0 * IMGPIX;
        const float* yb = ya + IMGPIX;
        const float* oa = o1 + (size_t)r0 * IMGPIX;
        const float* ob = oa + IMGPIX;

        float acc0[10], acc1[10];
        #pragma unroll
        for (int k = 0; k < 10; k++) { acc0[k] = 0.f; acc1[k] = 0.f; }

        #pragma unroll
        for (int it = 0; it < 13; it++) {
            int j  = lane + it * 64;
            int jc = j < IMGPIX ? j : IMGPIX - 1;
            float msk = j < IMGPIX ? 1.f : 0.f;
            float va = fmaxf(fmaf(ab.x, ya[jc], ab.y) + oa[jc], 0.f) * msk;
            float vb = fmaxf(fmaf(ab.x, yb[jc], ab.y) + ob[jc], 0.f) * msk;
            const float* fr = &fcT[jc * FC_LD];
            #pragma unroll
            for (int k = 0; k < 10; k++) {
                float f = fr[k];
                acc0[k] = fmaf(va, f, acc0[k]);
                acc1[k] = fmaf(vb, f, acc1[k]);
            }
        }
        #pragma unroll
        for (int k = 0; k < 10; k++) {
            #pragma unroll
            for (int off = 1; off < 64; off <<= 1) {
                acc0[k] += __shfl_xor(acc0[k], off, 64);
                acc1[k] += __shfl_xor(acc1[k], off, 64);
            }
        }
        float l0[10], l1[10];
        float m0 = -1e30f, m1 = -1e30f;
        #pragma unroll
        for (int k = 0; k < 10; k++) {
            l0[k] = fmaf(alpha, acc0[k], qkr[k]);
            l1[k] = fmaf(alpha, acc1[k], qkr[k]);
            m0 = fmaxf(m0, l0[k]);
            m1 = fmaxf(m1, l1[k]);
        }
        float se0 = 0.f, se1 = 0.f;
        #pragma unroll
        for (int k = 0; k < 10; k++) {
            se0 += __expf(l0[k] - m0);
            se1 += __expf(l1[k] - m1);
        }
        float lse0 = m0 + __logf(se0);
        float lse1 = m1 + __logf(se1);
        if (lane < 10) {
            out[(size_t)r0 * 10 + lane]       = l0[lane] - lse0;
            out[(size_t)(r0 + 1) * 10 + lane] = l1[lane] - lse1;
        }
    }
}

// Init: zero stats, compute qk[10] = (1-alpha)*c2*sum_{j%4==0} fcw[k,j] + fcb[k]
__global__ __launch_bounds__(256) void k_init(const float* __restrict__ theta,
        const float* __restrict__ fc_w, const float* __restrict__ fc_b,
        const float* __restrict__ alpha_p, float* __restrict__ qk, double* __restrict__ stats)
{
    const int t = threadIdx.x;
    for (int i = t; i < 4 * STAGE_DBL; i += 256) stats[i] = 0.0;
    if (t < 10) {
        float c = 1.f;
        #pragma unroll
        for (int i = 0; i < 24; i++) c *= cosf(theta[i] * 0.5f);
        float c2 = c * c;
        float s = 0.f;
        for (int j = 0; j < 784; j += 4) s += fc_w[t * 784 + j];
        qk[t] = (1.f - alpha_p[0]) * c2 * s + fc_b[t];
    }
}

extern "C" void kernel_launch(void* const* d_in, const int* in_sizes, int n_in,
                              void* d_out, int out_size, void* d_ws, size_t ws_size,
                              hipStream_t stream) {
    const float* x     = (const float*)d_in[0];
    const float* theta = (const float*)d_in[1];
    const float* r1_w1 = (const float*)d_in[2];
    const float* r1_g1 = (const float*)d_in[3];
    const float* r1_b1 = (const float*)d_in[4];
    const float* r1_w2 = (const float*)d_in[5];
    const float* r1_g2 = (const float*)d_in[6];
    const float* r1_b2 = (const float*)d_in[7];
    const float* r2_w1 = (const float*)d_in[8];
    const float* r2_g1 = (const float*)d_in[9];
    const float* r2_b1 = (const float*)d_in[10];
    const float* r2_w2 = (const float*)d_in[11];
    const float* r2_g2 = (const float*)d_in[12];
    const float* r2_b2 = (const float*)d_in[13];
    const float* fc_w  = (const float*)d_in[14];
    const float* fc_b  = (const float*)d_in[15];
    const float* alpha = (const float*)d_in[16];
    float* out = (float*)d_out;

    double* stats = (double*)d_ws;                       // 4 stages * 512 dbl = 16KB
    float*  qk    = (float*)((char*)d_ws + 16384);       // 10 floats
    float*  bufA  = (float*)((char*)d_ws + 32768);       // y1 then y3
    float*  bufB  = bufA + (size_t)NTOT;                 // y2 then y4
    float*  bufD  = bufB + (size_t)NTOT;                 // o1

    double* s_y1 = stats + 0 * STAGE_DBL;
    double* s_y2 = stats + 1 * STAGE_DBL;
    double* s_y3 = stats + 2 * STAGE_DBL;
    double* s_y4 = stats + 3 * STAGE_DBL;

    k_init<<<1, 256, 0, stream>>>(theta, fc_w, fc_b, alpha, qk, stats);
    k_conv_plain<<<2048, 256, 0, stream>>>(x, r1_w1, bufA, s_y1);
    k_conv_affine<<<2048, 256, 0, stream>>>(bufA, s_y1, r1_g1, r1_b1, r1_w2, bufB, s_y2);
    k_conv_resid<<<2048, 256, 0, stream>>>(bufB, x, s_y2, r1_g2, r1_b2, r2_w1, bufA, bufD, s_y3);
    k_conv_affine<<<2048, 256, 0, stream>>>(bufA, s_y3, r2_g1, r2_b1, r2_w2, bufB, s_y4);
    k_head<<<1024, 256, 0, stream>>>(bufB, bufD, s_y4, r2_g2, r2_b2, fc_w, qk, alpha, out);
}

// Round 8
// 110.375 us; speedup vs baseline: 1.3855x; 1.2496x over previous
//
#include <hip/hip_runtime.h>
#include <hip/hip_fp16.h>
#include <math.h>

#define BATCH   16384
#define IMGPIX  784           // 28*28
#define NTOT    (BATCH * IMGPIX)
#define NSLOT   64            // atomic spread slots per stage
#define SLOTSTR 8             // doubles per slot (64B stride); [0]=sum [1]=sumsq
#define STAGE_DBL (NSLOT * SLOTSTR)

// fp16 4-vector (8B) helpers
struct __align__(8) h4 { __half2 lo, hi; };
__device__ __forceinline__ h4 f4_to_h4(float4 v) {
    h4 r; r.lo = __floats2half2_rn(v.x, v.y); r.hi = __floats2half2_rn(v.z, v.w); return r;
}
__device__ __forceinline__ float4 h4_to_f4(h4 p) {
    float2 a = __half22float2(p.lo), b = __half22float2(p.hi);
    return make_float4(a.x, a.y, b.x, b.y);
}

// ---------------- stats helpers ----------------
__device__ __forceinline__ void wave_stats_atomic(double lsum, double lsq, double* slot) {
    #pragma unroll
    for (int off = 32; off >= 1; off >>= 1) {
        lsum += __shfl_down(lsum, off, 64);
        lsq  += __shfl_down(lsq,  off, 64);
    }
    if ((threadIdx.x & 63) == 0) {
        atomicAdd(&slot[0], lsum);
        atomicAdd(&slot[1], lsq);
    }
}

// Per-wave: reduce the 64 stat slots (2 doubles per lane), broadcast; returns
// (a,b) with bn(x) = a*x + b. No barrier needed.
__device__ __forceinline__ float2 stats_ab(const double* __restrict__ stats_in,
                                           float gamma, float beta) {
    int lane = threadIdx.x & 63;
    double s = stats_in[lane * SLOTSTR];
    double q = stats_in[lane * SLOTSTR + 1];
    #pragma unroll
    for (int off = 32; off >= 1; off >>= 1) {
        s += __shfl_down(s, off, 64);
        q += __shfl_down(q, off, 64);
    }
    s = __shfl(s, 0, 64);
    q = __shfl(q, 0, 64);
    const double INV_N = 1.0 / (double)NTOT;
    double mean = s * INV_N;
    double var  = q * INV_N - mean * mean;
    float rstd = 1.0f / sqrtf((float)var + 1e-5f);
    float a  = gamma * rstd;
    float bb = beta - (float)mean * a;
    return make_float2(a, bb);
}

// ---------------- strip conv core ----------------
// Grid: 2048 blocks = 512 image-groups x 4 strips. Strip s owns output rows
// r0..r0+6 (r0 = 7s), consumes conv-input rows r0-1..r0+7 (zero outside the
// image — zeroing on the ACTIVATED value, since reference pads h).
// Lane layout: lane = i*8 + c4 (i = image-in-wave 0..7, c4 = 0..6 column
// quad, c4==7 idle). Horizontal halo via shfl.

__device__ __forceinline__ float4 hrow(float wl, float wc, float wr,
                                       float L, float4 v, float R) {
    float4 h;
    h.x = fmaf(wl, L,   fmaf(wc, v.x, wr * v.y));
    h.y = fmaf(wl, v.x, fmaf(wc, v.y, wr * v.z));
    h.z = fmaf(wl, v.y, fmaf(wc, v.z, wr * v.w));
    h.w = fmaf(wl, v.z, fmaf(wc, v.w, wr * R));
    return h;
}

// conv outputs are stored fp16
__device__ __forceinline__ void emit_row(__half* dst, int r, float4 o, float mf,
                                         double& lsum, double& lsq, bool act) {
    if (act) *(h4*)(dst + r * 28) = f4_to_h4(o);
    float s4 = (o.x + o.y) + (o.z + o.w);
    float q4 = fmaf(o.x, o.x, fmaf(o.y, o.y, fmaf(o.z, o.z, o.w * o.w)));
    lsum += (double)(mf * s4);
    lsq  += (double)(mf * q4);
}

#define LANE_SETUP()                                                          \
    const int t = threadIdx.x;                                                \
    const int lane = t & 63;                                                  \
    const int widx = t >> 6;                                                  \
    const int c4   = lane & 7;                                                \
    const bool act = (c4 < 7);                                                \
    const float mf = act ? 1.f : 0.f;                                         \
    const int c4c  = c4 < 7 ? c4 : 6;  /* clamp idle lane addresses */        \
    const int g    = blockIdx.x & 511;   /* image group */                    \
    const int s    = blockIdx.x >> 9;    /* strip 0..3 */                     \
    const int r0   = s * 7;                                                   \
    const int rtop = (r0 > 0)  ? (r0 - 1) : 0;   /* clamped halo rows */      \
    const int rbot = (r0 < 21) ? (r0 + 7) : 27;                               \
    const int img  = g * 32 + widx * 8 + (lane >> 3);                         \
    const size_t ibase = (size_t)img * IMGPIX + c4c * 4;

// One pipeline step for conv-input row k (global row r0-1+k); emits row
// r0+k-2 for k>=2.
#define CONV_STEP(k, v)                                                       \
    {                                                                         \
        float L = __shfl_up((v).w, 1, 64);  if (c4 == 0) L = 0.f;             \
        float R = __shfl_down((v).x, 1, 64); if (c4 == 6) R = 0.f;            \
        float4 h2 = hrow(w9[6], w9[7], w9[8], L, (v), R);                     \
        float4 h1 = hrow(w9[3], w9[4], w9[5], L, (v), R);                     \
        float4 h0 = hrow(w9[0], w9[1], w9[2], L, (v), R);                     \
        accA.x += h2.x; accA.y += h2.y; accA.z += h2.z; accA.w += h2.w;       \
        if ((k) >= 2) emit_row(dst, r0 + (k) - 2, accA, mf, lsum, lsq, act);  \
        accA.x = accB.x + h1.x; accA.y = accB.y + h1.y;                       \
        accA.z = accB.z + h1.z; accA.w = accB.w + h1.w;                       \
        accB = h0;                                                            \
    }

// Zero the ACTIVATED conv-input value on out-of-image halo rows.
#define HALO_ZERO(k, v)                                                       \
    if ((k) == 0 && r0 == 0)  (v) = ZERO4;                                    \
    if ((k) == 8 && r0 == 21) (v) = ZERO4;

#define ZERO4 make_float4(0.f, 0.f, 0.f, 0.f)

// Pass 1: y1 = conv(x, w); stats(y1).  x is f32, y1 fp16.
__global__ __launch_bounds__(256, 5) void k_conv_plain(const float* __restrict__ in,
        const float* __restrict__ w, __half* __restrict__ out, double* __restrict__ stats_out)
{
    LANE_SETUP();
    float w9[9];
    #pragma unroll
    for (int i = 0; i < 9; i++) w9[i] = w[i];
    const float* src = in + ibase;
    __half* dst = out + (size_t)img * IMGPIX + c4 * 4;

    float4 vb[9];
    vb[0] = *(const float4*)(src + rtop * 28);
    #pragma unroll
    for (int k = 1; k < 8; k++) vb[k] = *(const float4*)(src + (r0 - 1 + k) * 28);
    vb[8] = *(const float4*)(src + rbot * 28);
    __builtin_amdgcn_sched_barrier(0);

    float4 accA = ZERO4, accB = ZERO4;
    double lsum = 0.0, lsq = 0.0;
    #pragma unroll
    for (int k = 0; k < 9; k++) {
        float4 v = vb[k];
        HALO_ZERO(k, v);                   // plain conv input = x, pad 0
        CONV_STEP(k, v);
    }
    wave_stats_atomic(lsum, lsq, &stats_out[((blockIdx.x * 4 + widx) & (NSLOT - 1)) * SLOTSTR]);
}

// Pass 2/4: h = relu(bn(in)); y = conv(h, w); stats(y).  in/out fp16.
__global__ __launch_bounds__(256, 8) void k_conv_affine(const __half* __restrict__ in,
        const double* __restrict__ stats_in,
        const float* __restrict__ gamma, const float* __restrict__ beta,
        const float* __restrict__ w, __half* __restrict__ out, double* __restrict__ stats_out)
{
    LANE_SETUP();
    float2 ab = stats_ab(stats_in, gamma[0], beta[0]);
    float w9[9];
    #pragma unroll
    for (int i = 0; i < 9; i++) w9[i] = w[i];
    const __half* src = in + ibase;
    __half* dst = out + (size_t)img * IMGPIX + c4 * 4;

    h4 vb[9];
    vb[0] = *(const h4*)(src + rtop * 28);
    #pragma unroll
    for (int k = 1; k < 8; k++) vb[k] = *(const h4*)(src + (r0 - 1 + k) * 28);
    vb[8] = *(const h4*)(src + rbot * 28);
    __builtin_amdgcn_sched_barrier(0);

    float4 accA = ZERO4, accB = ZERO4;
    double lsum = 0.0, lsq = 0.0;
    #pragma unroll
    for (int k = 0; k < 9; k++) {
        float4 r4 = h4_to_f4(vb[k]);
        float4 v;
        v.x = fmaxf(fmaf(ab.x, r4.x, ab.y), 0.f);
        v.y = fmaxf(fmaf(ab.x, r4.y, ab.y), 0.f);
        v.z = fmaxf(fmaf(ab.x, r4.z, ab.y), 0.f);
        v.w = fmaxf(fmaf(ab.x, r4.w, ab.y), 0.f);
        HALO_ZERO(k, v);                   // pad AFTER activation (matches ref)
        CONV_STEP(k, v);
    }
    wave_stats_atomic(lsum, lsq, &stats_out[((blockIdx.x * 4 + widx) & (NSLOT - 1)) * SLOTSTR]);
}

// Pass 3: o1 = relu(bn(y2) + x) [stored fp16, owned rows]; y3 = conv(o1, w); stats(y3)
__global__ __launch_bounds__(256, 5) void k_conv_resid(const __half* __restrict__ y2,
        const float* __restrict__ x, const double* __restrict__ stats_in,
        const float* __restrict__ gamma, const float* __restrict__ beta,
        const float* __restrict__ w, __half* __restrict__ y3_out,
        __half* __restrict__ o1_out, double* __restrict__ stats_out)
{
    LANE_SETUP();
    float2 ab = stats_ab(stats_in, gamma[0], beta[0]);
    float w9[9];
    #pragma unroll
    for (int i = 0; i < 9; i++) w9[i] = w[i];
    const __half* srcy = y2 + ibase;
    const float*  srcx = x + ibase;
    __half* dst  = y3_out + (size_t)img * IMGPIX + c4 * 4;
    __half* dsto = o1_out + (size_t)img * IMGPIX + c4 * 4;

    h4 yb[9];
    float4 xb[9];
    yb[0] = *(const h4*)(srcy + rtop * 28);
    xb[0] = *(const float4*)(srcx + rtop * 28);
    #pragma unroll
    for (int k = 1; k < 8; k++) {
        yb[k] = *(const h4*)(srcy + (r0 - 1 + k) * 28);
        xb[k] = *(const float4*)(srcx + (r0 - 1 + k) * 28);
    }
    yb[8] = *(const h4*)(srcy + rbot * 28);
    xb[8] = *(const float4*)(srcx + rbot * 28);
    __builtin_amdgcn_sched_barrier(0);

    float4 accA = ZERO4, accB = ZERO4;
    double lsum = 0.0, lsq = 0.0;
    #pragma unroll
    for (int k = 0; k < 9; k++) {
        float4 r4 = h4_to_f4(yb[k]);
        float4 x4 = xb[k];
        float4 v;
        v.x = fmaxf(fmaf(ab.x, r4.x, ab.y) + x4.x, 0.f);
        v.y = fmaxf(fmaf(ab.x, r4.y, ab.y) + x4.y, 0.f);
        v.z = fmaxf(fmaf(ab.x, r4.z, ab.y) + x4.z, 0.f);
        v.w = fmaxf(fmaf(ab.x, r4.w, ab.y) + x4.w, 0.f);
        HALO_ZERO(k, v);
        if (act && k >= 1 && k <= 7)           // owned rows only (always in-image)
            *(h4*)(dsto + (r0 - 1 + k) * 28) = f4_to_h4(v);
        CONV_STEP(k, v);
    }
    wave_stats_atomic(lsum, lsq, &stats_out[((blockIdx.x * 4 + widx) & (NSLOT - 1)) * SLOTSTR]);
}

// Pass 5: o2 = relu(bn(y4)+o1); logits = alpha*(o2@fcW^T)+qk; log_softmax
// 1024 blocks x 16 rows: fcT staged once per block, rows processed in pairs.
#define FC_LD 11
__global__ __launch_bounds__(256) void k_head(const __half* __restrict__ y4,
        const __half* __restrict__ o1, const double* __restrict__ stats_in,
        const float* __restrict__ gamma, const float* __restrict__ beta,
        const float* __restrict__ fc_w, const float* __restrict__ qk,
        const float* __restrict__ alpha_p, float* __restrict__ out)
{
    __shared__ float fcT[IMGPIX * FC_LD];
    const int t = threadIdx.x;
    float2 ab = stats_ab(stats_in, gamma[0], beta[0]);
    for (int i = t; i < 7840; i += 256) {
        int k = i / 784;
        int j = i - k * 784;
        fcT[j * FC_LD + k] = fc_w[i];
    }
    float alpha = alpha_p[0];
    float qkr[10];
    #pragma unroll
    for (int k = 0; k < 10; k++) qkr[k] = qk[k];
    __syncthreads();

    const int wid  = t >> 6;
    const int lane = t & 63;
    const int rbase = blockIdx.x * 16 + wid * 4;   // 4 rows per wave

    #pragma unroll
    for (int rp = 0; rp < 2; rp++) {
        const int r0 = rbase + rp * 2;
        const __half* ya = y4 + (size_t)r0 * IMGPIX;
        const __half* yb = ya + IMGPIX;
        const __half* oa = o1 + (size_t)r0 * IMGPIX;
        const __half* ob = oa + IMGPIX;

        float acc0[10], acc1[10];
        #pragma unroll
        for (int k = 0; k < 10; k++) { acc0[k] = 0.f; acc1[k] = 0.f; }

        #pragma unroll
        for (int it = 0; it < 13; it++) {
            int j  = lane + it * 64;
            int jc = j < IMGPIX ? j : IMGPIX - 1;
            float msk = j < IMGPIX ? 1.f : 0.f;
            float va = fmaxf(fmaf(ab.x, __half2float(ya[jc]), ab.y) + __half2float(oa[jc]), 0.f) * msk;
            float vb = fmaxf(fmaf(ab.x, __half2float(yb[jc]), ab.y) + __half2float(ob[jc]), 0.f) * msk;
            const float* fr = &fcT[jc * FC_LD];
            #pragma unroll
            for (int k = 0; k < 10; k++) {
                float f = fr[k];
                acc0[k] = fmaf(va, f, acc0[k]);
                acc1[k] = fmaf(vb, f, acc1[k]);
            }
        }
        #pragma unroll
        for (int k = 0; k < 10; k++) {
            #pragma unroll
            for (int off = 1; off < 64; off <<= 1) {
                acc0[k] += __shfl_xor(acc0[k], off, 64);
                acc1[k] += __shfl_xor(acc1[k], off, 64);
            }
        }
        float l0[10], l1[10];
        float m0 = -1e30f, m1 = -1e30f;
        #pragma unroll
        for (int k = 0; k < 10; k++) {
            l0[k] = fmaf(alpha, acc0[k], qkr[k]);
            l1[k] = fmaf(alpha, acc1[k], qkr[k]);
            m0 = fmaxf(m0, l0[k]);
            m1 = fmaxf(m1, l1[k]);
        }
        float se0 = 0.f, se1 = 0.f;
        #pragma unroll
        for (int k = 0; k < 10; k++) {
            se0 += __expf(l0[k] - m0);
            se1 += __expf(l1[k] - m1);
        }
        float lse0 = m0 + __logf(se0);
        float lse1 = m1 + __logf(se1);
        if (lane < 10) {
            out[(size_t)r0 * 10 + lane]       = l0[lane] - lse0;
            out[(size_t)(r0 + 1) * 10 + lane] = l1[lane] - lse1;
        }
    }
}

// Init: zero stats, compute qk[10] = (1-alpha)*c2*sum_{j%4==0} fcw[k,j] + fcb[k]
__global__ __launch_bounds__(256) void k_init(const float* __restrict__ theta,
        const float* __restrict__ fc_w, const float* __restrict__ fc_b,
        const float* __restrict__ alpha_p, float* __restrict__ qk, double* __restrict__ stats)
{
    const int t = threadIdx.x;
    for (int i = t; i < 4 * STAGE_DBL; i += 256) stats[i] = 0.0;
    if (t < 10) {
        float c = 1.f;
        #pragma unroll
        for (int i = 0; i < 24; i++) c *= cosf(theta[i] * 0.5f);
        float c2 = c * c;
        float s = 0.f;
        for (int j = 0; j < 784; j += 4) s += fc_w[t * 784 + j];
        qk[t] = (1.f - alpha_p[0]) * c2 * s + fc_b[t];
    }
}

extern "C" void kernel_launch(void* const* d_in, const int* in_sizes, int n_in,
                              void* d_out, int out_size, void* d_ws, size_t ws_size,
                              hipStream_t stream) {
    const float* x     = (const float*)d_in[0];
    const float* theta = (const float*)d_in[1];
    const float* r1_w1 = (const float*)d_in[2];
    const float* r1_g1 = (const float*)d_in[3];
    const float* r1_b1 = (const float*)d_in[4];
    const float* r1_w2 = (const float*)d_in[5];
    const float* r1_g2 = (const float*)d_in[6];
    const float* r1_b2 = (const float*)d_in[7];
    const float* r2_w1 = (const float*)d_in[8];
    const float* r2_g1 = (const float*)d_in[9];
    const float* r2_b1 = (const float*)d_in[10];
    const float* r2_w2 = (const float*)d_in[11];
    const float* r2_g2 = (const float*)d_in[12];
    const float* r2_b2 = (const float*)d_in[13];
    const float* fc_w  = (const float*)d_in[14];
    const float* fc_b  = (const float*)d_in[15];
    const float* alpha = (const float*)d_in[16];
    float* out = (float*)d_out;

    double* stats = (double*)d_ws;                       // 4 stages * 512 dbl = 16KB
    float*  qk    = (float*)((char*)d_ws + 16384);       // 10 floats
    __half* bufA  = (__half*)((char*)d_ws + 32768);      // y1 then y3
    __half* bufB  = bufA + (size_t)NTOT;                 // y2 then y4
    __half* bufD  = bufB + (size_t)NTOT;                 // o1

    double* s_y1 = stats + 0 * STAGE_DBL;
    double* s_y2 = stats + 1 * STAGE_DBL;
    double* s_y3 = stats + 2 * STAGE_DBL;
    double* s_y4 = stats + 3 * STAGE_DBL;

    k_init<<<1, 256, 0, stream>>>(theta, fc_w, fc_b, alpha, qk, stats);
    k_conv_plain<<<2048, 256, 0, stream>>>(x, r1_w1, bufA, s_y1);
    k_conv_affine<<<2048, 256, 0, stream>>>(bufA, s_y1, r1_g1, r1_b1, r1_w2, bufB, s_y2);
    k_conv_resid<<<2048, 256, 0, stream>>>(bufB, x, s_y2, r1_g2, r1_b2, r2_w1, bufA, bufD, s_y3);
    k_conv_affine<<<2048, 256, 0, stream>>>(bufA, s_y3, r2_g1, r2_b1, r2_w2, bufB, s_y4);
    k_head<<<1024, 256, 0, stream>>>(bufB, bufD, s_y4, r2_g2, r2_b2, fc_w, qk, alpha, out);
}

// Round 9
// 108.525 us; speedup vs baseline: 1.4091x; 1.0170x over previous
//
#include <hip/hip_runtime.h>
#include <hip/hip_fp16.h>
#include <math.h>

#define BATCH   16384
#define IMGPIX  784           // 28*28
#define NTOT    (BATCH * IMGPIX)
#define NSLOT   64            // atomic spread slots per stage
#define SLOTSTR 8             // doubles per slot (64B stride); [0]=sum [1]=sumsq
#define STAGE_DBL (NSLOT * SLOTSTR)
// Tiled fp16 layout: [G=img/8][r=0..27][c4=0..6][i=img%8][px=0..3]
// row-group = 224 halfs (448B, contiguous per wave); image-group = 6272 halfs.
#define TROW 224
#define TGRP 6272

// fp16 4-vector (8B) helpers
struct __align__(8) h4 { __half2 lo, hi; };
__device__ __forceinline__ h4 f4_to_h4(float4 v) {
    h4 r; r.lo = __floats2half2_rn(v.x, v.y); r.hi = __floats2half2_rn(v.z, v.w); return r;
}
__device__ __forceinline__ float4 h4_to_f4(h4 p) {
    float2 a = __half22float2(p.lo), b = __half22float2(p.hi);
    return make_float4(a.x, a.y, b.x, b.y);
}

// ---------------- stats helpers ----------------
__device__ __forceinline__ void wave_stats_atomic(double lsum, double lsq, double* slot) {
    #pragma unroll
    for (int off = 32; off >= 1; off >>= 1) {
        lsum += __shfl_down(lsum, off, 64);
        lsq  += __shfl_down(lsq,  off, 64);
    }
    if ((threadIdx.x & 63) == 0) {
        atomicAdd(&slot[0], lsum);
        atomicAdd(&slot[1], lsq);
    }
}

__device__ __forceinline__ float2 stats_ab(const double* __restrict__ stats_in,
                                           float gamma, float beta) {
    int lane = threadIdx.x & 63;
    double s = stats_in[lane * SLOTSTR];
    double q = stats_in[lane * SLOTSTR + 1];
    #pragma unroll
    for (int off = 32; off >= 1; off >>= 1) {
        s += __shfl_down(s, off, 64);
        q += __shfl_down(q, off, 64);
    }
    s = __shfl(s, 0, 64);
    q = __shfl(q, 0, 64);
    const double INV_N = 1.0 / (double)NTOT;
    double mean = s * INV_N;
    double var  = q * INV_N - mean * mean;
    float rstd = 1.0f / sqrtf((float)var + 1e-5f);
    float a  = gamma * rstd;
    float bb = beta - (float)mean * a;
    return make_float2(a, bb);
}

// ---------------- strip conv core ----------------
__device__ __forceinline__ float4 hrow(float wl, float wc, float wr,
                                       float L, float4 v, float R) {
    float4 h;
    h.x = fmaf(wl, L,   fmaf(wc, v.x, wr * v.y));
    h.y = fmaf(wl, v.x, fmaf(wc, v.y, wr * v.z));
    h.z = fmaf(wl, v.y, fmaf(wc, v.z, wr * v.w));
    h.w = fmaf(wl, v.z, fmaf(wc, v.w, wr * R));
    return h;
}

// conv outputs stored fp16 in tiled layout (row stride TROW halfs)
__device__ __forceinline__ void emit_row(__half* dst, int r, float4 o, float mf,
                                         double& lsum, double& lsq, bool act) {
    if (act) *(h4*)(dst + r * TROW) = f4_to_h4(o);
    float s4 = (o.x + o.y) + (o.z + o.w);
    float q4 = fmaf(o.x, o.x, fmaf(o.y, o.y, fmaf(o.z, o.z, o.w * o.w)));
    lsum += (double)(mf * s4);
    lsq  += (double)(mf * q4);
}

#define LANE_SETUP()                                                          \
    const int t = threadIdx.x;                                                \
    const int lane = t & 63;                                                  \
    const int widx = t >> 6;                                                  \
    const int c4   = lane & 7;                                                \
    const bool act = (c4 < 7);                                                \
    const float mf = act ? 1.f : 0.f;                                         \
    const int c4c  = c4 < 7 ? c4 : 6;  /* clamp idle lane addresses */        \
    const int g    = blockIdx.x & 511;   /* image group-of-32 */              \
    const int s    = blockIdx.x >> 9;    /* strip 0..3 */                     \
    const int r0   = s * 7;                                                   \
    const int rtop = (r0 > 0)  ? (r0 - 1) : 0;   /* clamped halo rows */      \
    const int rbot = (r0 < 21) ? (r0 + 7) : 27;                               \
    const int i8   = lane >> 3;                                               \
    const int G    = g * 4 + widx;       /* 8-image group 0..2047 */          \
    const int img  = G * 8 + i8;                                              \
    const size_t xbase = (size_t)img * IMGPIX + c4c * 4;          /* f32 x */ \
    const size_t tbR   = (size_t)G * TGRP + c4c * 32 + i8 * 4;    /* tiled */ \
    const size_t tbW   = (size_t)G * TGRP + c4  * 32 + i8 * 4;

// One pipeline step for conv-input row k (global row r0-1+k); emits row
// r0+k-2 for k>=2.
#define CONV_STEP(k, v)                                                       \
    {                                                                         \
        float L = __shfl_up((v).w, 1, 64);  if (c4 == 0) L = 0.f;             \
        float R = __shfl_down((v).x, 1, 64); if (c4 == 6) R = 0.f;            \
        float4 h2 = hrow(w9[6], w9[7], w9[8], L, (v), R);                     \
        float4 h1 = hrow(w9[3], w9[4], w9[5], L, (v), R);                     \
        float4 h0 = hrow(w9[0], w9[1], w9[2], L, (v), R);                     \
        accA.x += h2.x; accA.y += h2.y; accA.z += h2.z; accA.w += h2.w;       \
        if ((k) >= 2) emit_row(dst, r0 + (k) - 2, accA, mf, lsum, lsq, act);  \
        accA.x = accB.x + h1.x; accA.y = accB.y + h1.y;                       \
        accA.z = accB.z + h1.z; accA.w = accB.w + h1.w;                       \
        accB = h0;                                                            \
    }

// Zero the ACTIVATED conv-input value on out-of-image halo rows.
#define HALO_ZERO(k, v)                                                       \
    if ((k) == 0 && r0 == 0)  (v) = ZERO4;                                    \
    if ((k) == 8 && r0 == 21) (v) = ZERO4;

#define ZERO4 make_float4(0.f, 0.f, 0.f, 0.f)

// Pass 1: y1 = conv(x, w); stats(y1).  x f32 row-major, y1 fp16 tiled.
__global__ __launch_bounds__(256, 8) void k_conv_plain(const float* __restrict__ in,
        const float* __restrict__ w, __half* __restrict__ out, double* __restrict__ stats_out)
{
    LANE_SETUP();
    float w9[9];
    #pragma unroll
    for (int i = 0; i < 9; i++) w9[i] = w[i];
    const float* src = in + xbase;
    __half* dst = out + tbW;

    float4 vb[9];
    vb[0] = *(const float4*)(src + rtop * 28);
    #pragma unroll
    for (int k = 1; k < 8; k++) vb[k] = *(const float4*)(src + (r0 - 1 + k) * 28);
    vb[8] = *(const float4*)(src + rbot * 28);
    __builtin_amdgcn_sched_barrier(0);

    float4 accA = ZERO4, accB = ZERO4;
    double lsum = 0.0, lsq = 0.0;
    #pragma unroll
    for (int k = 0; k < 9; k++) {
        float4 v = vb[k];
        HALO_ZERO(k, v);                   // plain conv input = x, pad 0
        CONV_STEP(k, v);
    }
    wave_stats_atomic(lsum, lsq, &stats_out[((blockIdx.x * 4 + widx) & (NSLOT - 1)) * SLOTSTR]);
}

// Pass 2/4: h = relu(bn(in)); y = conv(h, w); stats(y).  in/out fp16 tiled.
__global__ __launch_bounds__(256, 8) void k_conv_affine(const __half* __restrict__ in,
        const double* __restrict__ stats_in,
        const float* __restrict__ gamma, const float* __restrict__ beta,
        const float* __restrict__ w, __half* __restrict__ out, double* __restrict__ stats_out)
{
    LANE_SETUP();
    float2 ab = stats_ab(stats_in, gamma[0], beta[0]);
    float w9[9];
    #pragma unroll
    for (int i = 0; i < 9; i++) w9[i] = w[i];
    const __half* src = in + tbR;
    __half* dst = out + tbW;

    h4 vb[9];
    vb[0] = *(const h4*)(src + rtop * TROW);
    #pragma unroll
    for (int k = 1; k < 8; k++) vb[k] = *(const h4*)(src + (r0 - 1 + k) * TROW);
    vb[8] = *(const h4*)(src + rbot * TROW);
    __builtin_amdgcn_sched_barrier(0);

    float4 accA = ZERO4, accB = ZERO4;
    double lsum = 0.0, lsq = 0.0;
    #pragma unroll
    for (int k = 0; k < 9; k++) {
        float4 r4 = h4_to_f4(vb[k]);
        float4 v;
        v.x = fmaxf(fmaf(ab.x, r4.x, ab.y), 0.f);
        v.y = fmaxf(fmaf(ab.x, r4.y, ab.y), 0.f);
        v.z = fmaxf(fmaf(ab.x, r4.z, ab.y), 0.f);
        v.w = fmaxf(fmaf(ab.x, r4.w, ab.y), 0.f);
        HALO_ZERO(k, v);                   // pad AFTER activation (matches ref)
        CONV_STEP(k, v);
    }
    wave_stats_atomic(lsum, lsq, &stats_out[((blockIdx.x * 4 + widx) & (NSLOT - 1)) * SLOTSTR]);
}

// Pass 3: o1 = relu(bn(y2) + x) [stored fp16 tiled, owned rows]; y3 = conv(o1, w)
__global__ __launch_bounds__(256, 6) void k_conv_resid(const __half* __restrict__ y2,
        const float* __restrict__ x, const double* __restrict__ stats_in,
        const float* __restrict__ gamma, const float* __restrict__ beta,
        const float* __restrict__ w, __half* __restrict__ y3_out,
        __half* __restrict__ o1_out, double* __restrict__ stats_out)
{
    LANE_SETUP();
    float2 ab = stats_ab(stats_in, gamma[0], beta[0]);
    float w9[9];
    #pragma unroll
    for (int i = 0; i < 9; i++) w9[i] = w[i];
    const __half* srcy = y2 + tbR;
    const float*  srcx = x + xbase;
    __half* dst  = y3_out + tbW;
    __half* dsto = o1_out + tbW;

    h4 yb[9];
    float4 xb[9];
    yb[0] = *(const h4*)(srcy + rtop * TROW);
    xb[0] = *(const float4*)(srcx + rtop * 28);
    #pragma unroll
    for (int k = 1; k < 8; k++) {
        yb[k] = *(const h4*)(srcy + (r0 - 1 + k) * TROW);
        xb[k] = *(const float4*)(srcx + (r0 - 1 + k) * 28);
    }
    yb[8] = *(const h4*)(srcy + rbot * TROW);
    xb[8] = *(const float4*)(srcx + rbot * 28);
    __builtin_amdgcn_sched_barrier(0);

    float4 accA = ZERO4, accB = ZERO4;
    double lsum = 0.0, lsq = 0.0;
    #pragma unroll
    for (int k = 0; k < 9; k++) {
        float4 r4 = h4_to_f4(yb[k]);
        float4 x4 = xb[k];
        float4 v;
        v.x = fmaxf(fmaf(ab.x, r4.x, ab.y) + x4.x, 0.f);
        v.y = fmaxf(fmaf(ab.x, r4.y, ab.y) + x4.y, 0.f);
        v.z = fmaxf(fmaf(ab.x, r4.z, ab.y) + x4.z, 0.f);
        v.w = fmaxf(fmaf(ab.x, r4.w, ab.y) + x4.w, 0.f);
        HALO_ZERO(k, v);
        if (act && k >= 1 && k <= 7)           // owned rows only (always in-image)
            *(h4*)(dsto + (r0 - 1 + k) * TROW) = f4_to_h4(v);
        CONV_STEP(k, v);
    }
    wave_stats_atomic(lsum, lsq, &stats_out[((blockIdx.x * 4 + widx) & (NSLOT - 1)) * SLOTSTR]);
}

// Pass 5: o2 = relu(bn(y4)+o1); logits = alpha*(o2@fcW^T)+qk; log_softmax
// One wave = one 8-image group. Lane (i8,c4) owns a 4-px column strip.
// fcK in LDS is class-major (= fc_w layout, straight copy); lanes with equal
// c4 broadcast-read the same float4. Class reduce = 3 shfl_xor over c4 bits.
__global__ __launch_bounds__(256) void k_head(const __half* __restrict__ y4,
        const __half* __restrict__ o1, const double* __restrict__ stats_in,
        const float* __restrict__ gamma, const float* __restrict__ beta,
        const float* __restrict__ fc_w, const float* __restrict__ qk,
        const float* __restrict__ alpha_p, float* __restrict__ out)
{
    __shared__ float fcK[7840];
    const int t = threadIdx.x;
    float2 ab = stats_ab(stats_in, gamma[0], beta[0]);
    for (int idx = t; idx < 7840; idx += 256) fcK[idx] = fc_w[idx];
    float alpha = alpha_p[0];
    float qkr[10];
    #pragma unroll
    for (int k = 0; k < 10; k++) qkr[k] = qk[k];
    __syncthreads();

    const int lane = t & 63;
    const int widx = t >> 6;
    const int c4   = lane & 7;
    const int i8   = lane >> 3;
    const int c4c  = c4 < 7 ? c4 : 6;
    const float mf = (c4 < 7) ? 1.f : 0.f;
    const int G    = blockIdx.x * 4 + widx;        // grid 512 -> G 0..2047
    const size_t tb = (size_t)G * TGRP + c4c * 32 + i8 * 4;
    const __half* ya = y4 + tb;
    const __half* oa = o1 + tb;

    float acc[10];
    #pragma unroll
    for (int k = 0; k < 10; k++) acc[k] = 0.f;

    #pragma unroll 7
    for (int r = 0; r < 28; r++) {
        float4 yf = h4_to_f4(*(const h4*)(ya + r * TROW));
        float4 of = h4_to_f4(*(const h4*)(oa + r * TROW));
        float4 v;
        v.x = fmaxf(fmaf(ab.x, yf.x, ab.y) + of.x, 0.f);
        v.y = fmaxf(fmaf(ab.x, yf.y, ab.y) + of.y, 0.f);
        v.z = fmaxf(fmaf(ab.x, yf.z, ab.y) + of.z, 0.f);
        v.w = fmaxf(fmaf(ab.x, yf.w, ab.y) + of.w, 0.f);
        const float* fb = &fcK[r * 28 + c4c * 4];
        #pragma unroll
        for (int k = 0; k < 10; k++) {
            const float4 f = *(const float4*)(fb + k * 784);
            acc[k] = fmaf(v.x, f.x, fmaf(v.y, f.y, fmaf(v.z, f.z, fmaf(v.w, f.w, acc[k]))));
        }
    }
    #pragma unroll
    for (int k = 0; k < 10; k++) {
        acc[k] *= mf;                              // zero idle-lane duplicates
        acc[k] += __shfl_xor(acc[k], 1, 64);
        acc[k] += __shfl_xor(acc[k], 2, 64);
        acc[k] += __shfl_xor(acc[k], 4, 64);
    }
    float l[10];
    float m = -1e30f;
    #pragma unroll
    for (int k = 0; k < 10; k++) {
        l[k] = fmaf(alpha, acc[k], qkr[k]);
        m = fmaxf(m, l[k]);
    }
    float se = 0.f;
    #pragma unroll
    for (int k = 0; k < 10; k++) se += __expf(l[k] - m);
    float lse = m + __logf(se);
    if (c4 == 0) {
        int img = G * 8 + i8;
        #pragma unroll
        for (int k = 0; k < 10; k++) out[(size_t)img * 10 + k] = l[k] - lse;
    }
}

// Init: zero stats, compute qk[10] = (1-alpha)*c2*sum_{j%4==0} fcw[k,j] + fcb[k]
__global__ __launch_bounds__(256) void k_init(const float* __restrict__ theta,
        const float* __restrict__ fc_w, const float* __restrict__ fc_b,
        const float* __restrict__ alpha_p, float* __restrict__ qk, double* __restrict__ stats)
{
    const int t = threadIdx.x;
    for (int i = t; i < 4 * STAGE_DBL; i += 256) stats[i] = 0.0;
    if (t < 10) {
        float c = 1.f;
        #pragma unroll
        for (int i = 0; i < 24; i++) c *= cosf(theta[i] * 0.5f);
        float c2 = c * c;
        float s = 0.f;
        for (int j = 0; j < 784; j += 4) s += fc_w[t * 784 + j];
        qk[t] = (1.f - alpha_p[0]) * c2 * s + fc_b[t];
    }
}

extern "C" void kernel_launch(void* const* d_in, const int* in_sizes, int n_in,
                              void* d_out, int out_size, void* d_ws, size_t ws_size,
                              hipStream_t stream) {
    const float* x     = (const float*)d_in[0];
    const float* theta = (const float*)d_in[1];
    const float* r1_w1 = (const float*)d_in[2];
    const float* r1_g1 = (const float*)d_in[3];
    const float* r1_b1 = (const float*)d_in[4];
    const float* r1_w2 = (const float*)d_in[5];
    const float* r1_g2 = (const float*)d_in[6];
    const float* r1_b2 = (const float*)d_in[7];
    const float* r2_w1 = (const float*)d_in[8];
    const float* r2_g1 = (const float*)d_in[9];
    const float* r2_b1 = (const float*)d_in[10];
    const float* r2_w2 = (const float*)d_in[11];
    const float* r2_g2 = (const float*)d_in[12];
    const float* r2_b2 = (const float*)d_in[13];
    const float* fc_w  = (const float*)d_in[14];
    const float* fc_b  = (const float*)d_in[15];
    const float* alpha = (const float*)d_in[16];
    float* out = (float*)d_out;

    double* stats = (double*)d_ws;                       // 4 stages * 512 dbl = 16KB
    float*  qk    = (float*)((char*)d_ws + 16384);       // 10 floats
    __half* bufA  = (__half*)((char*)d_ws + 32768);      // y1 then y3 (tiled)
    __half* bufB  = bufA + (size_t)NTOT;                 // y2 then y4 (tiled)
    __half* bufD  = bufB + (size_t)NTOT;                 // o1 (tiled)

    double* s_y1 = stats + 0 * STAGE_DBL;
    double* s_y2 = stats + 1 * STAGE_DBL;
    double* s_y3 = stats + 2 * STAGE_DBL;
    double* s_y4 = stats + 3 * STAGE_DBL;

    k_init<<<1, 256, 0, stream>>>(theta, fc_w, fc_b, alpha, qk, stats);
    k_conv_plain<<<2048, 256, 0, stream>>>(x, r1_w1, bufA, s_y1);
    k_conv_affine<<<2048, 256, 0, stream>>>(bufA, s_y1, r1_g1, r1_b1, r1_w2, bufB, s_y2);
    k_conv_resid<<<2048, 256, 0, stream>>>(bufB, x, s_y2, r1_g2, r1_b2, r2_w1, bufA, bufD, s_y3);
    k_conv_affine<<<2048, 256, 0, stream>>>(bufA, s_y3, r2_g1, r2_b1, r2_w2, bufB, s_y4);
    k_head<<<512, 256, 0, stream>>>(bufB, bufD, s_y4, r2_g2, r2_b2, fc_w, qk, alpha, out);
}

// Round 10
// 107.235 us; speedup vs baseline: 1.4260x; 1.0120x over previous
//
#include <hip/hip_runtime.h>
#include <hip/hip_fp16.h>
#include <math.h>

#define BATCH   16384
#define IMGPIX  784           // 28*28
#define NTOT    (BATCH * IMGPIX)
#define NSLOT   64            // atomic spread slots per stage
#define SLOTSTR 8             // doubles per slot (64B stride); [0]=sum [1]=sumsq
#define STAGE_DBL (NSLOT * SLOTSTR)
// Tiled fp16 layout: [G=img/8][r=0..27][c4=0..6][i=img%8][px=0..3]
// row-group = 224 halfs (448B, contiguous per wave); image-group = 6272 halfs.
#define TROW 224
#define TGRP 6272

// fp16 4-vector (8B) helpers
struct __align__(8) h4 { __half2 lo, hi; };
__device__ __forceinline__ h4 f4_to_h4(float4 v) {
    h4 r; r.lo = __floats2half2_rn(v.x, v.y); r.hi = __floats2half2_rn(v.z, v.w); return r;
}
__device__ __forceinline__ float4 h4_to_f4(h4 p) {
    float2 a = __half22float2(p.lo), b = __half22float2(p.hi);
    return make_float4(a.x, a.y, b.x, b.y);
}

// ---------------- stats helpers ----------------
__device__ __forceinline__ void wave_stats_atomic(double lsum, double lsq, double* slot) {
    #pragma unroll
    for (int off = 32; off >= 1; off >>= 1) {
        lsum += __shfl_down(lsum, off, 64);
        lsq  += __shfl_down(lsq,  off, 64);
    }
    if ((threadIdx.x & 63) == 0) {
        atomicAdd(&slot[0], lsum);
        atomicAdd(&slot[1], lsq);
    }
}

__device__ __forceinline__ float2 stats_ab(const double* __restrict__ stats_in,
                                           float gamma, float beta) {
    int lane = threadIdx.x & 63;
    double s = stats_in[lane * SLOTSTR];
    double q = stats_in[lane * SLOTSTR + 1];
    #pragma unroll
    for (int off = 32; off >= 1; off >>= 1) {
        s += __shfl_down(s, off, 64);
        q += __shfl_down(q, off, 64);
    }
    s = __shfl(s, 0, 64);
    q = __shfl(q, 0, 64);
    const double INV_N = 1.0 / (double)NTOT;
    double mean = s * INV_N;
    double var  = q * INV_N - mean * mean;
    float rstd = 1.0f / sqrtf((float)var + 1e-5f);
    float a  = gamma * rstd;
    float bb = beta - (float)mean * a;
    return make_float2(a, bb);
}

// ---------------- strip conv core ----------------
__device__ __forceinline__ float4 hrow(float wl, float wc, float wr,
                                       float L, float4 v, float R) {
    float4 h;
    h.x = fmaf(wl, L,   fmaf(wc, v.x, wr * v.y));
    h.y = fmaf(wl, v.x, fmaf(wc, v.y, wr * v.z));
    h.z = fmaf(wl, v.y, fmaf(wc, v.z, wr * v.w));
    h.w = fmaf(wl, v.z, fmaf(wc, v.w, wr * R));
    return h;
}

// conv outputs stored fp16 in tiled layout (row stride TROW halfs)
__device__ __forceinline__ void emit_row(__half* dst, int r, float4 o, float mf,
                                         double& lsum, double& lsq, bool act) {
    if (act) *(h4*)(dst + r * TROW) = f4_to_h4(o);
    float s4 = (o.x + o.y) + (o.z + o.w);
    float q4 = fmaf(o.x, o.x, fmaf(o.y, o.y, fmaf(o.z, o.z, o.w * o.w)));
    lsum += (double)(mf * s4);
    lsq  += (double)(mf * q4);
}

#define LANE_SETUP()                                                          \
    const int t = threadIdx.x;                                                \
    const int lane = t & 63;                                                  \
    const int widx = t >> 6;                                                  \
    const int c4   = lane & 7;                                                \
    const bool act = (c4 < 7);                                                \
    const float mf = act ? 1.f : 0.f;                                         \
    const int c4c  = c4 < 7 ? c4 : 6;  /* clamp idle lane addresses */        \
    const int g    = blockIdx.x & 511;   /* image group-of-32 */              \
    const int s    = blockIdx.x >> 9;    /* strip 0..3 */                     \
    const int r0   = s * 7;                                                   \
    const int rtop = (r0 > 0)  ? (r0 - 1) : 0;   /* clamped halo rows */      \
    const int rbot = (r0 < 21) ? (r0 + 7) : 27;                               \
    const int i8   = lane >> 3;                                               \
    const int G    = g * 4 + widx;       /* 8-image group 0..2047 */          \
    const int img  = G * 8 + i8;                                              \
    const size_t xbase = (size_t)img * IMGPIX + c4c * 4;          /* f32 x */ \
    const size_t tbR   = (size_t)G * TGRP + c4c * 32 + i8 * 4;    /* tiled */ \
    const size_t tbW   = (size_t)G * TGRP + c4  * 32 + i8 * 4;

// One pipeline step for conv-input row k (global row r0-1+k); emits row
// r0+k-2 for k>=2.
#define CONV_STEP(k, v)                                                       \
    {                                                                         \
        float L = __shfl_up((v).w, 1, 64);  if (c4 == 0) L = 0.f;             \
        float R = __shfl_down((v).x, 1, 64); if (c4 == 6) R = 0.f;            \
        float4 h2 = hrow(w9[6], w9[7], w9[8], L, (v), R);                     \
        float4 h1 = hrow(w9[3], w9[4], w9[5], L, (v), R);                     \
        float4 h0 = hrow(w9[0], w9[1], w9[2], L, (v), R);                     \
        accA.x += h2.x; accA.y += h2.y; accA.z += h2.z; accA.w += h2.w;       \
        if ((k) >= 2) emit_row(dst, r0 + (k) - 2, accA, mf, lsum, lsq, act);  \
        accA.x = accB.x + h1.x; accA.y = accB.y + h1.y;                       \
        accA.z = accB.z + h1.z; accA.w = accB.w + h1.w;                       \
        accB = h0;                                                            \
    }

// Zero the ACTIVATED conv-input value on out-of-image halo rows.
#define HALO_ZERO(k, v)                                                       \
    if ((k) == 0 && r0 == 0)  (v) = ZERO4;                                    \
    if ((k) == 8 && r0 == 21) (v) = ZERO4;

#define ZERO4 make_float4(0.f, 0.f, 0.f, 0.f)

// Pass 1: y1 = conv(x, w); stats(y1); also emit x16 (tiled fp16 copy of x).
__global__ __launch_bounds__(256, 8) void k_conv_plain(const float* __restrict__ in,
        const float* __restrict__ w, __half* __restrict__ out,
        __half* __restrict__ x16_out, double* __restrict__ stats_out)
{
    LANE_SETUP();
    float w9[9];
    #pragma unroll
    for (int i = 0; i < 9; i++) w9[i] = w[i];
    const float* src = in + xbase;
    __half* dst  = out + tbW;
    __half* dstx = x16_out + tbW;

    float4 vb[9];
    vb[0] = *(const float4*)(src + rtop * 28);
    #pragma unroll
    for (int k = 1; k < 8; k++) vb[k] = *(const float4*)(src + (r0 - 1 + k) * 28);
    vb[8] = *(const float4*)(src + rbot * 28);
    __builtin_amdgcn_sched_barrier(0);

    float4 accA = ZERO4, accB = ZERO4;
    double lsum = 0.0, lsq = 0.0;
    #pragma unroll
    for (int k = 0; k < 9; k++) {
        float4 v = vb[k];
        if (act && k >= 1 && k <= 7)           // owned rows: raw x copy
            *(h4*)(dstx + (r0 - 1 + k) * TROW) = f4_to_h4(vb[k]);
        HALO_ZERO(k, v);                       // plain conv input = x, pad 0
        CONV_STEP(k, v);
    }
    wave_stats_atomic(lsum, lsq, &stats_out[((blockIdx.x * 4 + widx) & (NSLOT - 1)) * SLOTSTR]);
}

// Pass 2/4: h = relu(bn(in)); y = conv(h, w); stats(y).  in/out fp16 tiled.
__global__ __launch_bounds__(256, 8) void k_conv_affine(const __half* __restrict__ in,
        const double* __restrict__ stats_in,
        const float* __restrict__ gamma, const float* __restrict__ beta,
        const float* __restrict__ w, __half* __restrict__ out, double* __restrict__ stats_out)
{
    LANE_SETUP();
    float2 ab = stats_ab(stats_in, gamma[0], beta[0]);
    float w9[9];
    #pragma unroll
    for (int i = 0; i < 9; i++) w9[i] = w[i];
    const __half* src = in + tbR;
    __half* dst = out + tbW;

    h4 vb[9];
    vb[0] = *(const h4*)(src + rtop * TROW);
    #pragma unroll
    for (int k = 1; k < 8; k++) vb[k] = *(const h4*)(src + (r0 - 1 + k) * TROW);
    vb[8] = *(const h4*)(src + rbot * TROW);
    __builtin_amdgcn_sched_barrier(0);

    float4 accA = ZERO4, accB = ZERO4;
    double lsum = 0.0, lsq = 0.0;
    #pragma unroll
    for (int k = 0; k < 9; k++) {
        float4 r4 = h4_to_f4(vb[k]);
        float4 v;
        v.x = fmaxf(fmaf(ab.x, r4.x, ab.y), 0.f);
        v.y = fmaxf(fmaf(ab.x, r4.y, ab.y), 0.f);
        v.z = fmaxf(fmaf(ab.x, r4.z, ab.y), 0.f);
        v.w = fmaxf(fmaf(ab.x, r4.w, ab.y), 0.f);
        HALO_ZERO(k, v);                   // pad AFTER activation (matches ref)
        CONV_STEP(k, v);
    }
    wave_stats_atomic(lsum, lsq, &stats_out[((blockIdx.x * 4 + widx) & (NSLOT - 1)) * SLOTSTR]);
}

// Pass 3: o1 = relu(bn(y2) + x16) [stored fp16 tiled, owned rows]; y3 = conv(o1, w)
__global__ __launch_bounds__(256, 8) void k_conv_resid(const __half* __restrict__ y2,
        const __half* __restrict__ x16, const double* __restrict__ stats_in,
        const float* __restrict__ gamma, const float* __restrict__ beta,
        const float* __restrict__ w, __half* __restrict__ y3_out,
        __half* __restrict__ o1_out, double* __restrict__ stats_out)
{
    LANE_SETUP();
    float2 ab = stats_ab(stats_in, gamma[0], beta[0]);
    float w9[9];
    #pragma unroll
    for (int i = 0; i < 9; i++) w9[i] = w[i];
    const __half* srcy = y2 + tbR;
    const __half* srcx = x16 + tbR;
    __half* dst  = y3_out + tbW;
    __half* dsto = o1_out + tbW;

    h4 yb[9], xb[9];
    yb[0] = *(const h4*)(srcy + rtop * TROW);
    xb[0] = *(const h4*)(srcx + rtop * TROW);
    #pragma unroll
    for (int k = 1; k < 8; k++) {
        yb[k] = *(const h4*)(srcy + (r0 - 1 + k) * TROW);
        xb[k] = *(const h4*)(srcx + (r0 - 1 + k) * TROW);
    }
    yb[8] = *(const h4*)(srcy + rbot * TROW);
    xb[8] = *(const h4*)(srcx + rbot * TROW);
    __builtin_amdgcn_sched_barrier(0);

    float4 accA = ZERO4, accB = ZERO4;
    double lsum = 0.0, lsq = 0.0;
    #pragma unroll
    for (int k = 0; k < 9; k++) {
        float4 r4 = h4_to_f4(yb[k]);
        float4 x4 = h4_to_f4(xb[k]);
        float4 v;
        v.x = fmaxf(fmaf(ab.x, r4.x, ab.y) + x4.x, 0.f);
        v.y = fmaxf(fmaf(ab.x, r4.y, ab.y) + x4.y, 0.f);
        v.z = fmaxf(fmaf(ab.x, r4.z, ab.y) + x4.z, 0.f);
        v.w = fmaxf(fmaf(ab.x, r4.w, ab.y) + x4.w, 0.f);
        HALO_ZERO(k, v);
        if (act && k >= 1 && k <= 7)           // owned rows only (always in-image)
            *(h4*)(dsto + (r0 - 1 + k) * TROW) = f4_to_h4(v);
        CONV_STEP(k, v);
    }
    wave_stats_atomic(lsum, lsq, &stats_out[((blockIdx.x * 4 + widx) & (NSLOT - 1)) * SLOTSTR]);
}

// Pass 5: o2 = relu(bn(y4)+o1); logits = alpha*(o2@fcW^T)+qk; log_softmax
// One wave = one 8-image group. Lane (i8,c4) owns a 4-px column strip.
__global__ __launch_bounds__(256) void k_head(const __half* __restrict__ y4,
        const __half* __restrict__ o1, const double* __restrict__ stats_in,
        const float* __restrict__ gamma, const float* __restrict__ beta,
        const float* __restrict__ fc_w, const float* __restrict__ qk,
        const float* __restrict__ alpha_p, float* __restrict__ out)
{
    __shared__ float fcK[7840];
    const int t = threadIdx.x;
    float2 ab = stats_ab(stats_in, gamma[0], beta[0]);
    for (int idx = t; idx < 7840; idx += 256) fcK[idx] = fc_w[idx];
    float alpha = alpha_p[0];
    float qkr[10];
    #pragma unroll
    for (int k = 0; k < 10; k++) qkr[k] = qk[k];
    __syncthreads();

    const int lane = t & 63;
    const int widx = t >> 6;
    const int c4   = lane & 7;
    const int i8   = lane >> 3;
    const int c4c  = c4 < 7 ? c4 : 6;
    const float mf = (c4 < 7) ? 1.f : 0.f;
    const int G    = blockIdx.x * 4 + widx;        // grid 512 -> G 0..2047
    const size_t tb = (size_t)G * TGRP + c4c * 32 + i8 * 4;
    const __half* ya = y4 + tb;
    const __half* oa = o1 + tb;

    float acc[10];
    #pragma unroll
    for (int k = 0; k < 10; k++) acc[k] = 0.f;

    #pragma unroll 7
    for (int r = 0; r < 28; r++) {
        float4 yf = h4_to_f4(*(const h4*)(ya + r * TROW));
        float4 of = h4_to_f4(*(const h4*)(oa + r * TROW));
        float4 v;
        v.x = fmaxf(fmaf(ab.x, yf.x, ab.y) + of.x, 0.f);
        v.y = fmaxf(fmaf(ab.x, yf.y, ab.y) + of.y, 0.f);
        v.z = fmaxf(fmaf(ab.x, yf.z, ab.y) + of.z, 0.f);
        v.w = fmaxf(fmaf(ab.x, yf.w, ab.y) + of.w, 0.f);
        const float* fb = &fcK[r * 28 + c4c * 4];
        #pragma unroll
        for (int k = 0; k < 10; k++) {
            const float4 f = *(const float4*)(fb + k * 784);
            acc[k] = fmaf(v.x, f.x, fmaf(v.y, f.y, fmaf(v.z, f.z, fmaf(v.w, f.w, acc[k]))));
        }
    }
    #pragma unroll
    for (int k = 0; k < 10; k++) {
        acc[k] *= mf;                              // zero idle-lane duplicates
        acc[k] += __shfl_xor(acc[k], 1, 64);
        acc[k] += __shfl_xor(acc[k], 2, 64);
        acc[k] += __shfl_xor(acc[k], 4, 64);
    }
    float l[10];
    float m = -1e30f;
    #pragma unroll
    for (int k = 0; k < 10; k++) {
        l[k] = fmaf(alpha, acc[k], qkr[k]);
        m = fmaxf(m, l[k]);
    }
    float se = 0.f;
    #pragma unroll
    for (int k = 0; k < 10; k++) se += __expf(l[k] - m);
    float lse = m + __logf(se);
    if (c4 == 0) {
        int img = G * 8 + i8;
        #pragma unroll
        for (int k = 0; k < 10; k++) out[(size_t)img * 10 + k] = l[k] - lse;
    }
}

// Init: zero stats, compute qk[10] = (1-alpha)*c2*sum_{j%4==0} fcw[k,j] + fcb[k]
// Parallel: 80 threads = 10 classes x 8 octants, 3-shuffle reduce per class.
__global__ __launch_bounds__(256) void k_init(const float* __restrict__ theta,
        const float* __restrict__ fc_w, const float* __restrict__ fc_b,
        const float* __restrict__ alpha_p, float* __restrict__ qk, double* __restrict__ stats)
{
    const int t = threadIdx.x;
    for (int i = t; i < 4 * STAGE_DBL; i += 256) stats[i] = 0.0;
    __shared__ float csum[10];
    if (t < 80) {
        int k = t >> 3, oct = t & 7;
        float s = 0.f;
        #pragma unroll
        for (int i = 0; i < 25; i++) {
            int p = oct + 8 * i;               // position among the 196 j%4==0 cols
            if (p < 196) s += fc_w[k * 784 + p * 4];
        }
        s += __shfl_xor(s, 1, 64);
        s += __shfl_xor(s, 2, 64);
        s += __shfl_xor(s, 4, 64);
        if (oct == 0) csum[k] = s;
    }
    __syncthreads();
    if (t < 10) {
        float c = 1.f;
        #pragma unroll
        for (int i = 0; i < 24; i++) c *= cosf(theta[i] * 0.5f);
        float c2 = c * c;
        qk[t] = (1.f - alpha_p[0]) * c2 * csum[t] + fc_b[t];
    }
}

extern "C" void kernel_launch(void* const* d_in, const int* in_sizes, int n_in,
                              void* d_out, int out_size, void* d_ws, size_t ws_size,
                              hipStream_t stream) {
    const float* x     = (const float*)d_in[0];
    const float* theta = (const float*)d_in[1];
    const float* r1_w1 = (const float*)d_in[2];
    const float* r1_g1 = (const float*)d_in[3];
    const float* r1_b1 = (const float*)d_in[4];
    const float* r1_w2 = (const float*)d_in[5];
    const float* r1_g2 = (const float*)d_in[6];
    const float* r1_b2 = (const float*)d_in[7];
    const float* r2_w1 = (const float*)d_in[8];
    const float* r2_g1 = (const float*)d_in[9];
    const float* r2_b1 = (const float*)d_in[10];
    const float* r2_w2 = (const float*)d_in[11];
    const float* r2_g2 = (const float*)d_in[12];
    const float* r2_b2 = (const float*)d_in[13];
    const float* fc_w  = (const float*)d_in[14];
    const float* fc_b  = (const float*)d_in[15];
    const float* alpha = (const float*)d_in[16];
    float* out = (float*)d_out;

    double* stats = (double*)d_ws;                       // 4 stages * 512 dbl = 16KB
    float*  qk    = (float*)((char*)d_ws + 16384);       // 10 floats
    __half* bufA  = (__half*)((char*)d_ws + 32768);      // y1 then y3 (tiled)
    __half* bufB  = bufA + (size_t)NTOT;                 // y2 then y4 (tiled)
    __half* bufD  = bufB + (size_t)NTOT;                 // o1 (tiled)
    __half* bufX  = bufD + (size_t)NTOT;                 // x16 (tiled)

    double* s_y1 = stats + 0 * STAGE_DBL;
    double* s_y2 = stats + 1 * STAGE_DBL;
    double* s_y3 = stats + 2 * STAGE_DBL;
    double* s_y4 = stats + 3 * STAGE_DBL;

    k_init<<<1, 256, 0, stream>>>(theta, fc_w, fc_b, alpha, qk, stats);
    k_conv_plain<<<2048, 256, 0, stream>>>(x, r1_w1, bufA, bufX, s_y1);
    k_conv_affine<<<2048, 256, 0, stream>>>(bufA, s_y1, r1_g1, r1_b1, r1_w2, bufB, s_y2);
    k_conv_resid<<<2048, 256, 0, stream>>>(bufB, bufX, s_y2, r1_g2, r1_b2, r2_w1, bufA, bufD, s_y3);
    k_conv_affine<<<2048, 256, 0, stream>>>(bufA, s_y3, r2_g1, r2_b1, r2_w2, bufB, s_y4);
    k_head<<<512, 256, 0, stream>>>(bufB, bufD, s_y4, r2_g2, r2_b2, fc_w, qk, alpha, out);
}